// Round 4
// baseline (176.791 us; speedup 1.0000x reference)
//
#include <hip/hip_runtime.h>
#include <cstdint>
#include <cstddef>

// ---------------------------------------------------------------------------
// ReLA block: y = LN2( (causal_relu( (LN1(x)Wq*s) (LN1(x)Wk)^T ) (LN1(x)Wv)) Wout )
// x: [2,2048,1024] fp32. HEADS=16, DIM_HEAD=64, DIM=1024. Output fp32.
// bf16 MFMA (16x16x32) everywhere, fp32 accumulate.
// R12: attn per-wave ILP. Parity argument (kt0 even, r1 odd) collapses the
//      iteration to uniform control flow: a participating wave always needs
//      BOTH staged tiles. Hoist both tiles' 32 ds_read_b128, then issue all
//      FOUR independent S-matmul streams (32 MFMA) before any Ss round-trip
//      (write->read latency hides under the other streams). s_setprio(1)
//      around the compute body (waves are role-diverse: drained lo-waves
//      stage at prio 0 while hi-waves MFMA at prio 1).
// ---------------------------------------------------------------------------

typedef __bf16 bf16_t;
typedef __bf16 bf16x8 __attribute__((ext_vector_type(8)));
typedef __bf16 bf16x4 __attribute__((ext_vector_type(4)));
typedef float  f32x4  __attribute__((ext_vector_type(4)));

#define DEV_INLINE __device__ __forceinline__

// async global->LDS, 16B per lane. LDS dest is wave-uniform base + lane*16.
DEV_INLINE void async_copy16(void* lds, const void* g) {
  __builtin_amdgcn_global_load_lds(
      (__attribute__((address_space(1))) void*)(g),
      (__attribute__((address_space(3))) void*)(lds), 16, 0, 0);
}

// ---------------------------------------------------------------------------
// prep: fused LN1 (blocks 0..4095) + wtrans(w_qkv) (4096..4863) +
//       wtrans(w_out) (4864..5119)
// ---------------------------------------------------------------------------
__global__ __launch_bounds__(256) void prep_kernel(
    const float* __restrict__ x, const float* __restrict__ g1,
    const float* __restrict__ b1, bf16_t* __restrict__ xn,
    const float* __restrict__ w_qkv, bf16_t* __restrict__ wqkvT,
    const float* __restrict__ w_out, bf16_t* __restrict__ woutT) {
  const int bid = blockIdx.x;
  const int t = threadIdx.x;
  if (bid < 4096) {
    // ---- LN1 row ----
    const int w = t >> 6, l = t & 63;
    const float* xr = x + (size_t)bid * 1024;
    float4 v = *(const float4*)(xr + t * 4);
    float s  = v.x + v.y + v.z + v.w;
    float s2 = v.x * v.x + v.y * v.y + v.z * v.z + v.w * v.w;
    #pragma unroll
    for (int off = 32; off >= 1; off >>= 1) {
      s  += __shfl_down(s, off);
      s2 += __shfl_down(s2, off);
    }
    __shared__ float red[8];
    if (l == 0) { red[w] = s; red[4 + w] = s2; }
    __syncthreads();
    s  = red[0] + red[1] + red[2] + red[3];
    s2 = red[4] + red[5] + red[6] + red[7];
    float mu  = s * (1.0f / 1024.0f);
    float var = s2 * (1.0f / 1024.0f) - mu * mu;
    float rs  = rsqrtf(var + 1e-5f);
    float4 gv = *(const float4*)(g1 + t * 4);
    float4 bv = *(const float4*)(b1 + t * 4);
    bf16x4 o;
    o[0] = (bf16_t)((v.x - mu) * rs * gv.x + bv.x);
    o[1] = (bf16_t)((v.y - mu) * rs * gv.y + bv.y);
    o[2] = (bf16_t)((v.z - mu) * rs * gv.z + bv.z);
    o[3] = (bf16_t)((v.w - mu) * rs * gv.w + bv.w);
    *(bf16x4*)(xn + (size_t)bid * 1024 + t * 4) = o;
  } else {
    // ---- weight transpose+convert: 64x64 tile ----
    const float* wsrc; bf16_t* wdst; int N, tile;
    if (bid < 4864) { wsrc = w_qkv; wdst = wqkvT; N = 3072; tile = bid - 4096; }
    else            { wsrc = w_out; wdst = woutT; N = 1024; tile = bid - 4864; }
    const int ntiles = N >> 6;
    const int n0 = (tile % ntiles) * 64, k0 = (tile / ntiles) * 64;
    __shared__ __align__(16) float tl[64][68];
    #pragma unroll
    for (int c = 0; c < 4; ++c) {
      int idx = c * 256 + t;
      int r = idx >> 4, c4 = (idx & 15) * 4;
      *(float4*)&tl[r][c4] = *(const float4*)(wsrc + (size_t)(k0 + r) * N + n0 + c4);
    }
    __syncthreads();
    #pragma unroll
    for (int c = 0; c < 2; ++c) {
      int idx = c * 256 + t;
      int nl = idx >> 3, kc = (idx & 7) * 8;
      bf16x8 o;
      #pragma unroll
      for (int ii = 0; ii < 8; ++ii) o[ii] = (bf16_t)tl[kc + ii][nl];
      *(bf16x8*)(wdst + (size_t)(n0 + nl) * 1024 + k0 + kc) = o;
    }
  }
}

// ---------------------------------------------------------------------------
// LN2 (fused split-K add, bf16 partials): z = z0 + z1 -> layernorm -> fp32
// ---------------------------------------------------------------------------
__global__ __launch_bounds__(256) void ln2_kernel(
    const bf16_t* __restrict__ z0, const bf16_t* __restrict__ z1,
    const float* __restrict__ g, const float* __restrict__ bta,
    float* __restrict__ out) {
  const int row = blockIdx.x;
  const int t = threadIdx.x, w = t >> 6, l = t & 63;
  bf16x4 a0 = *(const bf16x4*)(z0 + (size_t)row * 1024 + t * 4);
  bf16x4 a1 = *(const bf16x4*)(z1 + (size_t)row * 1024 + t * 4);
  float4 v;
  v.x = (float)a0[0] + (float)a1[0];
  v.y = (float)a0[1] + (float)a1[1];
  v.z = (float)a0[2] + (float)a1[2];
  v.w = (float)a0[3] + (float)a1[3];
  float s  = v.x + v.y + v.z + v.w;
  float s2 = v.x * v.x + v.y * v.y + v.z * v.z + v.w * v.w;
  #pragma unroll
  for (int off = 32; off >= 1; off >>= 1) {
    s  += __shfl_down(s, off);
    s2 += __shfl_down(s2, off);
  }
  __shared__ float red[8];
  if (l == 0) { red[w] = s; red[4 + w] = s2; }
  __syncthreads();
  s  = red[0] + red[1] + red[2] + red[3];
  s2 = red[4] + red[5] + red[6] + red[7];
  float mu  = s * (1.0f / 1024.0f);
  float var = s2 * (1.0f / 1024.0f) - mu * mu;
  float rs  = rsqrtf(var + 1e-5f);
  float4 gv = *(const float4*)(g + t * 4);
  float4 bv = *(const float4*)(bta + t * 4);
  float4 o;
  o.x = (v.x - mu) * rs * gv.x + bv.x;
  o.y = (v.y - mu) * rs * gv.y + bv.y;
  o.z = (v.z - mu) * rs * gv.z + bv.z;
  o.w = (v.w - mu) * rs * gv.w + bv.w;
  *(float4*)(out + (size_t)row * 1024 + t * 4) = o;
}

// ---------------------------------------------------------------------------
// GEMM: C[M,N] = A[M,1024] @ Bt[N,1024]^T, bf16 in, fp32 acc.
// BK=64, XOR-swizzled staging. KSPLIT=2: kz=0 -> C0, kz=1 -> C1 (bf16
// partials). EPI=1: qkv split epilogue -> q(*0.125)/k bf16 [b,h,2048,64],
// V written TRANSPOSED to C2: vT bf16 [b,h,64,2048] (vtrans fused).
// ---------------------------------------------------------------------------
template <int EPI, int KSPLIT>
__global__ __launch_bounds__(256, 3) void gemm128_kernel(
    const bf16_t* __restrict__ A, const bf16_t* __restrict__ Bt,
    void* __restrict__ C0, void* __restrict__ C1, void* __restrict__ C2) {
  __shared__ __align__(16) bf16_t As[128 * 64];  // 16 KB
  __shared__ __align__(16) bf16_t Bs[128 * 64];  // 16 KB
  const int t = threadIdx.x;
  const int w = t >> 6, l = t & 63, l15 = l & 15, quad = l >> 4;
  const int wy = w >> 1, wx = w & 1;
  const int m0 = blockIdx.y * 128, n0 = blockIdx.x * 128;
  const int kz = (KSPLIT > 1) ? blockIdx.z : 0;
  const int kt0 = kz * (16 / KSPLIT), kt1 = kt0 + (16 / KSPLIT);

  const int r_l = l >> 3;              // row within 8-row chunk
  const int u_src = (l & 7) ^ r_l;     // swizzled source 8-elem unit
  const int rswz = l15 & 7;            // read-side swizzle key

  f32x4 acc[4][4];
  #pragma unroll
  for (int i = 0; i < 4; ++i)
    #pragma unroll
    for (int j = 0; j < 4; ++j) acc[i][j] = (f32x4)0.0f;

  for (int kt = kt0; kt < kt1; ++kt) {
    __syncthreads();
    #pragma unroll
    for (int c = 0; c < 4; ++c) {
      int idx = w * 4 + c;             // 16 chunks of 512 elems
      int row = idx * 8 + r_l;         // 0..127
      async_copy16(&As[idx * 512], A + (size_t)(m0 + row) * 1024 + kt * 64 + u_src * 8);
      async_copy16(&Bs[idx * 512], Bt + (size_t)(n0 + row) * 1024 + kt * 64 + u_src * 8);
    }
    __syncthreads();
    #pragma unroll
    for (int kk = 0; kk < 2; ++kk) {
      bf16x8 af[4], bfr[4];
      #pragma unroll
      for (int i = 0; i < 4; ++i)
        af[i] = *(const bf16x8*)&As[(wy * 64 + i * 16 + l15) * 64 + (((kk * 4 + quad) ^ rswz) * 8)];
      #pragma unroll
      for (int j = 0; j < 4; ++j)
        bfr[j] = *(const bf16x8*)&Bs[(wx * 64 + j * 16 + l15) * 64 + (((kk * 4 + quad) ^ rswz) * 8)];
      #pragma unroll
      for (int i = 0; i < 4; ++i)
        #pragma unroll
        for (int j = 0; j < 4; ++j)
          acc[i][j] = __builtin_amdgcn_mfma_f32_16x16x32_bf16(af[i], bfr[j], acc[i][j], 0, 0, 0);
    }
  }

  if (EPI == 0) {
    bf16_t* C = (bf16_t*)(kz == 0 ? C0 : C1);   // bf16 partial destinations
    #pragma unroll
    for (int i = 0; i < 4; ++i)
      #pragma unroll
      for (int j = 0; j < 4; ++j)
        #pragma unroll
        for (int r = 0; r < 4; ++r) {
          int m = m0 + wy * 64 + i * 16 + quad * 4 + r;
          int n = n0 + wx * 64 + j * 16 + l15;
          C[(size_t)m * 1024 + n] = (bf16_t)acc[i][j][r];
        }
  } else {
    int nb = n0 + wx * 64;
    int which = nb >> 10;              // 0=q, 1=k, 2=v
    int head = (nb & 1023) >> 6;
    const int bq = m0 >> 11;           // batch (uniform per block: m0 multiple of 128)
    const int mb = (m0 & 2047) + wy * 64;
    if (which == 2) {
      // V: write transposed directly -> vT[b,h,d,pos]. acc[i][j][r] has r
      // contiguous in pos, so each lane stores a bf16x4 along pos.
      bf16_t* dst = (bf16_t*)C2 + ((size_t)(bq * 16 + head)) * 64 * 2048;
      #pragma unroll
      for (int i = 0; i < 4; ++i)
        #pragma unroll
        for (int j = 0; j < 4; ++j) {
          bf16x4 pk;
          #pragma unroll
          for (int r = 0; r < 4; ++r) pk[r] = (bf16_t)acc[i][j][r];
          int d = j * 16 + l15;
          int pos = mb + i * 16 + quad * 4;
          *(bf16x4*)(dst + (size_t)d * 2048 + pos) = pk;
        }
    } else {
      bf16_t* dst = which == 0 ? (bf16_t*)C0 : (bf16_t*)C1;
      float sc = which == 0 ? 0.125f : 1.0f;
      #pragma unroll
      for (int i = 0; i < 4; ++i)
        #pragma unroll
        for (int j = 0; j < 4; ++j)
          #pragma unroll
          for (int r = 0; r < 4; ++r) {
            int pos = mb + i * 16 + quad * 4 + r;
            int d = j * 16 + l15;
            dst[(((size_t)(bq * 16 + head)) * 2048 + pos) * 64 + d] =
                (bf16_t)(acc[i][j][r] * sc);
          }
    }
  }
}

// ---------------------------------------------------------------------------
// Causal ReLU attention, R12: uniform-work 512-thread blocks + deep ILP.
// Block (h=bx, j=by in [0,8), b=bz) handles rows {2j, 2j+1, 30-2j, 31-2j}:
//   waves 0-3 = pair-lo (rows 2j, 2j+1), waves 4-7 = pair-hi (30-2j, 31-2j).
// Parity: kt0=2i is even, r1 odd -> a participating wave (kt0 <= r0) always
// consumes BOTH tiles of the iteration; last iteration is diagonal (dg0).
// Per iteration: hoist 32 ds_read_b128 (both tiles), issue all 4 independent
// S-matmul streams, then the 4 Ss round-trips (write->read latency hidden).
// s_setprio(1) around compute (drained lo-waves stage at prio 0).
// 256 blocks = 1/CU exactly; 2 waves/SIMD (structural cap). LDS 82 KB.
// ---------------------------------------------------------------------------
__global__ __launch_bounds__(512, 2) void attn_kernel(
    const bf16_t* __restrict__ q, const bf16_t* __restrict__ k,
    const bf16_t* __restrict__ vT, bf16_t* __restrict__ out) {
  __shared__ __align__(16) bf16_t Ks[2][2][64 * 64];   // [dbuf][tile] 32 KB
  __shared__ __align__(16) bf16_t Vts[2][2][64 * 64];  // 32 KB
  __shared__ __align__(16) bf16_t Ss[2][64 * 72];      // [pair] 18 KB

  const int h = blockIdx.x, j = blockIdx.y, b = blockIdx.z;
  const int t = threadIdx.x;
  const int w = t >> 6, l = t & 63, l15 = l & 15, quad = l >> 4;
  const int pairSel = w >> 2;          // 0 = lo, 1 = hi
  const int wl = w & 3;                // wave within pair-group (16 queries)
  const size_t bh = (size_t)(b * 16 + h);
  const int r0 = pairSel ? 30 - 2 * j : 2 * j;
  const int r1 = r0 + 1;
  const int niter = 16 - j;            // tiles 0..31-2j, two per iteration

  const int r_l = l >> 3;              // row within 8-row chunk
  const int u_g = (l & 7) ^ r_l;       // swizzled source 8-elem unit
  const int rswz = l15 & 7;            // read-side swizzle key

  // stage 2 tiles (2*i2, 2*i2+1): 32 async ops spread over 8 waves
  auto stage_pair = [&](int buf, int i2) {
    #pragma unroll
    for (int c = 0; c < 4; ++c) {
      int op = w * 4 + c;              // 0..31
      int tau = op >> 4;               // which of the 2 tiles
      int rem = op & 15;
      int mK = rem >> 3;               // 0 = K, 1 = V
      int idx = rem & 7;               // chunk within tile
      int kt = 2 * i2 + tau;
      int row = idx * 8 + r_l;         // 0..63
      if (mK == 0)
        async_copy16(&Ks[buf][tau][idx * 512],
                     k + (bh * 2048 + kt * 64 + row) * 64 + u_g * 8);
      else
        async_copy16(&Vts[buf][tau][idx * 512],
                     vT + (bh * 64 + row) * 2048 + kt * 64 + u_g * 8);
    }
  };

  // read a staged tile's K/V fragments from LDS (once per tile, per wave)
  auto load_lds = [&](const bf16_t* Kb, const bf16_t* Vb,
                      bf16x8 (&bk)[2][4], bf16x8 (&bv)[2][4]) {
    #pragma unroll
    for (int kk = 0; kk < 2; ++kk)
      #pragma unroll
      for (int tj = 0; tj < 4; ++tj) {
        int u = ((kk * 4 + quad) ^ rswz) * 8;
        bk[kk][tj] = *(const bf16x8*)&Kb[(tj * 16 + l15) * 64 + u];
        bv[kk][tj] = *(const bf16x8*)&Vb[(tj * 16 + l15) * 64 + u];
      }
  };

  bf16x8 qa[2][2];   // B-operand fragments: lane l15 = query row, k = d
  {
    #pragma unroll
    for (int kk = 0; kk < 2; ++kk) {
      qa[0][kk] = *(const bf16x8*)(q + (bh * 2048 + r0 * 64 + wl * 16 + l15) * 64 + kk * 32 + quad * 8);
      qa[1][kk] = *(const bf16x8*)(q + (bh * 2048 + r1 * 64 + wl * 16 + l15) * 64 + kk * 32 + quad * 8);
    }
  }

  // acc[tj] = O^T block: lane col = pos (l15), regs = d = tj*16 + quad*4 + r
  f32x4 acc0[4], acc1[4];
  #pragma unroll
  for (int tj = 0; tj < 4; ++tj) { acc0[tj] = (f32x4)0.0f; acc1[tj] = (f32x4)0.0f; }

  // S^T matmul into registers (no LDS)
  auto sU = [&](f32x4 (&sacc)[4], bf16x8 (&qf)[2], bf16x8 (&bk)[2][4]) {
    #pragma unroll
    for (int tj = 0; tj < 4; ++tj) sacc[tj] = (f32x4)0.0f;
    #pragma unroll
    for (int kk = 0; kk < 2; ++kk)
      #pragma unroll
      for (int tj = 0; tj < 4; ++tj)
        sacc[tj] = __builtin_amdgcn_mfma_f32_16x16x32_bf16(bk[kk][tj], qf[kk], sacc[tj], 0, 0, 0);
  };
  // relu + mask + packed Ss write (wave-private rows of this pair's buffer)
  auto wU = [&](f32x4 (&sacc)[4], bool dg) {
    #pragma unroll
    for (int tj = 0; tj < 4; ++tj) {
      bf16x4 pk;
      #pragma unroll
      for (int r = 0; r < 4; ++r) {
        float v = fmaxf(sacc[tj][r], 0.0f);
        if (dg && (tj * 16 + quad * 4 + r > wl * 16 + l15)) v = 0.0f;
        pk[r] = (bf16_t)v;
      }
      *(bf16x4*)&Ss[pairSel][(wl * 16 + l15) * 72 + tj * 16 + quad * 4] = pk;
    }
  };
  // PV: read Ss as B-fragment, O^T += V^T.S
  auto pU = [&](f32x4 (&accr)[4], bf16x8 (&bv)[2][4]) {
    #pragma unroll
    for (int kk = 0; kk < 2; ++kk) {
      bf16x8 as_ = *(const bf16x8*)&Ss[pairSel][(wl * 16 + l15) * 72 + kk * 32 + quad * 8];
      #pragma unroll
      for (int tj = 0; tj < 4; ++tj)
        accr[tj] = __builtin_amdgcn_mfma_f32_16x16x32_bf16(bv[kk][tj], as_, accr[tj], 0, 0, 0);
    }
  };

  stage_pair(0, 0);
  for (int i = 0; i < niter; ++i) {
    __syncthreads();  // drains this buffer's async loads; fences reuse
    if (i + 1 < niter) stage_pair((i + 1) & 1, i + 1);
    const int buf = i & 1;
    const int kt0 = 2 * i;
    if (kt0 > r0) continue;            // pair-group done (lo waves, late iters)
    const bool dg0 = (kt0 == r0);      // diagonal iteration (kt1 == r1 too)
    // hoist BOTH tiles' fragments (32 ds_read_b128)
    bf16x8 bk0[2][4], bv0[2][4], bk1[2][4], bv1[2][4];
    load_lds(Ks[buf][0], Vts[buf][0], bk0, bv0);
    load_lds(Ks[buf][1], Vts[buf][1], bk1, bv1);
    __builtin_amdgcn_s_setprio(1);
    // all independent S-matmul streams first (up to 32 MFMA)
    f32x4 s0[4], s1[4], s2[4], s3[4];
    sU(s0, qa[0], bk0);
    sU(s1, qa[1], bk0);
    if (!dg0) sU(s2, qa[0], bk1);
    sU(s3, qa[1], bk1);
    // Ss round-trips (same-wave in-order DS keeps single buffer safe)
    wU(s0, dg0);   pU(acc0, bv0);
    wU(s1, false); pU(acc1, bv0);
    if (!dg0) { wU(s2, false); pU(acc0, bv1); }
    wU(s3, dg0);   pU(acc1, bv1);
    __builtin_amdgcn_s_setprio(0);
  }

  // epilogue: O^T regs -> out[b][pos][h*64+d], 4 d-contiguous per store
  #pragma unroll
  for (int tj = 0; tj < 4; ++tj) {
    bf16x4 p0, p1;
    #pragma unroll
    for (int r = 0; r < 4; ++r) { p0[r] = (bf16_t)acc0[tj][r]; p1[r] = (bf16_t)acc1[tj][r]; }
    int posA = r0 * 64 + wl * 16 + l15;
    int posB = r1 * 64 + wl * 16 + l15;
    int col = h * 64 + tj * 16 + quad * 4;
    *(bf16x4*)(out + ((size_t)b * 2048 + posA) * 1024 + col) = p0;
    *(bf16x4*)(out + ((size_t)b * 2048 + posB) * 1024 + col) = p1;
  }
}

// ---------------------------------------------------------------------------
// launch
// ---------------------------------------------------------------------------
extern "C" void kernel_launch(void* const* d_in, const int* in_sizes, int n_in,
                              void* d_out, int out_size, void* d_ws, size_t ws_size,
                              hipStream_t stream) {
  (void)in_sizes; (void)n_in; (void)out_size; (void)ws_size;
  const float* x     = (const float*)d_in[0];
  const float* ln1_g = (const float*)d_in[1];
  const float* ln1_b = (const float*)d_in[2];
  const float* w_qkv = (const float*)d_in[3];
  const float* w_out = (const float*)d_in[4];
  const float* ln2_g = (const float*)d_in[5];
  const float* ln2_b = (const float*)d_in[6];
  float* out = (float*)d_out;

  char* ws = (char*)d_ws;
  bf16_t* xn     = (bf16_t*)(ws + 0);          //  8,388,608  [4096,1024]
  bf16_t* wqkvT  = (bf16_t*)(ws + 8388608);    //  6,291,456  [3072,1024]
  bf16_t* woutT  = (bf16_t*)(ws + 14680064);   //  2,097,152  [1024,1024]
  bf16_t* qb     = (bf16_t*)(ws + 16777216);   //  8,388,608  [2,16,2048,64]
  bf16_t* kb     = (bf16_t*)(ws + 25165824);   //  8,388,608
  bf16_t* vTb    = (bf16_t*)(ws + 41943040);   //  8,388,608  [2,16,64,2048] (written by QKV epilogue)
  bf16_t* ao     = (bf16_t*)(ws + 50331648);   //  8,388,608  [4096,1024]
  bf16_t* zb0    = (bf16_t*)(ws + 58720256);   //  8,388,608  [4096,1024] bf16 partial
  bf16_t* zb1    = (bf16_t*)(ws + 67108864);   //  8,388,608  bf16 partial

  prep_kernel<<<5120, 256, 0, stream>>>(x, ln1_g, ln1_b, xn, w_qkv, wqkvT, w_out, woutT);
  gemm128_kernel<1, 1><<<dim3(24, 32), 256, 0, stream>>>(xn, wqkvT, qb, kb, vTb);
  attn_kernel<<<dim3(16, 8, 2), 512, 0, stream>>>(qb, kb, vTb, ao);
  gemm128_kernel<0, 2><<<dim3(8, 32, 2), 256, 0, stream>>>(ao, woutT, zb0, zb1, nullptr);
  ln2_kernel<<<4096, 256, 0, stream>>>(zb0, zb1, ln2_g, ln2_b, out);
}

// Round 5
// 169.784 us; speedup vs baseline: 1.0413x; 1.0413x over previous
//
#include <hip/hip_runtime.h>
#include <cstdint>
#include <cstddef>

// ---------------------------------------------------------------------------
// ReLA block: y = LN2( (causal_relu( (LN1(x)Wq*s) (LN1(x)Wk)^T ) (LN1(x)Wv)) Wout )
// x: [2,2048,1024] fp32. HEADS=16, DIM_HEAD=64, DIM=1024. Output fp32.
// bf16 MFMA (16x16x32) everywhere, fp32 accumulate.
// R13: revert R12's register-heavy hoist (VGPR blowup -> +5.4 µs). Back to
//      R11's verified loop, with ONE contained change: per-unit Ss buffers
//      (Ss[pair][unit]) so the two units' Ss round-trips overlap:
//      wU(s0); wU(s1); pU(acc0); pU(acc1) — unit1's LDS write->read latency
//      hides under unit0's 8 PV MFMAs. No new live fragments (0 extra VGPR),
//      no setprio. LDS 100 KB (1 block/CU, grid is 256 = 1/CU anyway).
// ---------------------------------------------------------------------------

typedef __bf16 bf16_t;
typedef __bf16 bf16x8 __attribute__((ext_vector_type(8)));
typedef __bf16 bf16x4 __attribute__((ext_vector_type(4)));
typedef float  f32x4  __attribute__((ext_vector_type(4)));

#define DEV_INLINE __device__ __forceinline__

// async global->LDS, 16B per lane. LDS dest is wave-uniform base + lane*16.
DEV_INLINE void async_copy16(void* lds, const void* g) {
  __builtin_amdgcn_global_load_lds(
      (__attribute__((address_space(1))) void*)(g),
      (__attribute__((address_space(3))) void*)(lds), 16, 0, 0);
}

// ---------------------------------------------------------------------------
// prep: fused LN1 (blocks 0..4095) + wtrans(w_qkv) (4096..4863) +
//       wtrans(w_out) (4864..5119)
// ---------------------------------------------------------------------------
__global__ __launch_bounds__(256) void prep_kernel(
    const float* __restrict__ x, const float* __restrict__ g1,
    const float* __restrict__ b1, bf16_t* __restrict__ xn,
    const float* __restrict__ w_qkv, bf16_t* __restrict__ wqkvT,
    const float* __restrict__ w_out, bf16_t* __restrict__ woutT) {
  const int bid = blockIdx.x;
  const int t = threadIdx.x;
  if (bid < 4096) {
    // ---- LN1 row ----
    const int w = t >> 6, l = t & 63;
    const float* xr = x + (size_t)bid * 1024;
    float4 v = *(const float4*)(xr + t * 4);
    float s  = v.x + v.y + v.z + v.w;
    float s2 = v.x * v.x + v.y * v.y + v.z * v.z + v.w * v.w;
    #pragma unroll
    for (int off = 32; off >= 1; off >>= 1) {
      s  += __shfl_down(s, off);
      s2 += __shfl_down(s2, off);
    }
    __shared__ float red[8];
    if (l == 0) { red[w] = s; red[4 + w] = s2; }
    __syncthreads();
    s  = red[0] + red[1] + red[2] + red[3];
    s2 = red[4] + red[5] + red[6] + red[7];
    float mu  = s * (1.0f / 1024.0f);
    float var = s2 * (1.0f / 1024.0f) - mu * mu;
    float rs  = rsqrtf(var + 1e-5f);
    float4 gv = *(const float4*)(g1 + t * 4);
    float4 bv = *(const float4*)(b1 + t * 4);
    bf16x4 o;
    o[0] = (bf16_t)((v.x - mu) * rs * gv.x + bv.x);
    o[1] = (bf16_t)((v.y - mu) * rs * gv.y + bv.y);
    o[2] = (bf16_t)((v.z - mu) * rs * gv.z + bv.z);
    o[3] = (bf16_t)((v.w - mu) * rs * gv.w + bv.w);
    *(bf16x4*)(xn + (size_t)bid * 1024 + t * 4) = o;
  } else {
    // ---- weight transpose+convert: 64x64 tile ----
    const float* wsrc; bf16_t* wdst; int N, tile;
    if (bid < 4864) { wsrc = w_qkv; wdst = wqkvT; N = 3072; tile = bid - 4096; }
    else            { wsrc = w_out; wdst = woutT; N = 1024; tile = bid - 4864; }
    const int ntiles = N >> 6;
    const int n0 = (tile % ntiles) * 64, k0 = (tile / ntiles) * 64;
    __shared__ __align__(16) float tl[64][68];
    #pragma unroll
    for (int c = 0; c < 4; ++c) {
      int idx = c * 256 + t;
      int r = idx >> 4, c4 = (idx & 15) * 4;
      *(float4*)&tl[r][c4] = *(const float4*)(wsrc + (size_t)(k0 + r) * N + n0 + c4);
    }
    __syncthreads();
    #pragma unroll
    for (int c = 0; c < 2; ++c) {
      int idx = c * 256 + t;
      int nl = idx >> 3, kc = (idx & 7) * 8;
      bf16x8 o;
      #pragma unroll
      for (int ii = 0; ii < 8; ++ii) o[ii] = (bf16_t)tl[kc + ii][nl];
      *(bf16x8*)(wdst + (size_t)(n0 + nl) * 1024 + k0 + kc) = o;
    }
  }
}

// ---------------------------------------------------------------------------
// LN2 (fused split-K add, bf16 partials): z = z0 + z1 -> layernorm -> fp32
// ---------------------------------------------------------------------------
__global__ __launch_bounds__(256) void ln2_kernel(
    const bf16_t* __restrict__ z0, const bf16_t* __restrict__ z1,
    const float* __restrict__ g, const float* __restrict__ bta,
    float* __restrict__ out) {
  const int row = blockIdx.x;
  const int t = threadIdx.x, w = t >> 6, l = t & 63;
  bf16x4 a0 = *(const bf16x4*)(z0 + (size_t)row * 1024 + t * 4);
  bf16x4 a1 = *(const bf16x4*)(z1 + (size_t)row * 1024 + t * 4);
  float4 v;
  v.x = (float)a0[0] + (float)a1[0];
  v.y = (float)a0[1] + (float)a1[1];
  v.z = (float)a0[2] + (float)a1[2];
  v.w = (float)a0[3] + (float)a1[3];
  float s  = v.x + v.y + v.z + v.w;
  float s2 = v.x * v.x + v.y * v.y + v.z * v.z + v.w * v.w;
  #pragma unroll
  for (int off = 32; off >= 1; off >>= 1) {
    s  += __shfl_down(s, off);
    s2 += __shfl_down(s2, off);
  }
  __shared__ float red[8];
  if (l == 0) { red[w] = s; red[4 + w] = s2; }
  __syncthreads();
  s  = red[0] + red[1] + red[2] + red[3];
  s2 = red[4] + red[5] + red[6] + red[7];
  float mu  = s * (1.0f / 1024.0f);
  float var = s2 * (1.0f / 1024.0f) - mu * mu;
  float rs  = rsqrtf(var + 1e-5f);
  float4 gv = *(const float4*)(g + t * 4);
  float4 bv = *(const float4*)(bta + t * 4);
  float4 o;
  o.x = (v.x - mu) * rs * gv.x + bv.x;
  o.y = (v.y - mu) * rs * gv.y + bv.y;
  o.z = (v.z - mu) * rs * gv.z + bv.z;
  o.w = (v.w - mu) * rs * gv.w + bv.w;
  *(float4*)(out + (size_t)row * 1024 + t * 4) = o;
}

// ---------------------------------------------------------------------------
// GEMM: C[M,N] = A[M,1024] @ Bt[N,1024]^T, bf16 in, fp32 acc.
// BK=64, XOR-swizzled staging. KSPLIT=2: kz=0 -> C0, kz=1 -> C1 (bf16
// partials). EPI=1: qkv split epilogue -> q(*0.125)/k bf16 [b,h,2048,64],
// V written TRANSPOSED to C2: vT bf16 [b,h,64,2048] (vtrans fused).
// ---------------------------------------------------------------------------
template <int EPI, int KSPLIT>
__global__ __launch_bounds__(256, 3) void gemm128_kernel(
    const bf16_t* __restrict__ A, const bf16_t* __restrict__ Bt,
    void* __restrict__ C0, void* __restrict__ C1, void* __restrict__ C2) {
  __shared__ __align__(16) bf16_t As[128 * 64];  // 16 KB
  __shared__ __align__(16) bf16_t Bs[128 * 64];  // 16 KB
  const int t = threadIdx.x;
  const int w = t >> 6, l = t & 63, l15 = l & 15, quad = l >> 4;
  const int wy = w >> 1, wx = w & 1;
  const int m0 = blockIdx.y * 128, n0 = blockIdx.x * 128;
  const int kz = (KSPLIT > 1) ? blockIdx.z : 0;
  const int kt0 = kz * (16 / KSPLIT), kt1 = kt0 + (16 / KSPLIT);

  const int r_l = l >> 3;              // row within 8-row chunk
  const int u_src = (l & 7) ^ r_l;     // swizzled source 8-elem unit
  const int rswz = l15 & 7;            // read-side swizzle key

  f32x4 acc[4][4];
  #pragma unroll
  for (int i = 0; i < 4; ++i)
    #pragma unroll
    for (int j = 0; j < 4; ++j) acc[i][j] = (f32x4)0.0f;

  for (int kt = kt0; kt < kt1; ++kt) {
    __syncthreads();
    #pragma unroll
    for (int c = 0; c < 4; ++c) {
      int idx = w * 4 + c;             // 16 chunks of 512 elems
      int row = idx * 8 + r_l;         // 0..127
      async_copy16(&As[idx * 512], A + (size_t)(m0 + row) * 1024 + kt * 64 + u_src * 8);
      async_copy16(&Bs[idx * 512], Bt + (size_t)(n0 + row) * 1024 + kt * 64 + u_src * 8);
    }
    __syncthreads();
    #pragma unroll
    for (int kk = 0; kk < 2; ++kk) {
      bf16x8 af[4], bfr[4];
      #pragma unroll
      for (int i = 0; i < 4; ++i)
        af[i] = *(const bf16x8*)&As[(wy * 64 + i * 16 + l15) * 64 + (((kk * 4 + quad) ^ rswz) * 8)];
      #pragma unroll
      for (int j = 0; j < 4; ++j)
        bfr[j] = *(const bf16x8*)&Bs[(wx * 64 + j * 16 + l15) * 64 + (((kk * 4 + quad) ^ rswz) * 8)];
      #pragma unroll
      for (int i = 0; i < 4; ++i)
        #pragma unroll
        for (int j = 0; j < 4; ++j)
          acc[i][j] = __builtin_amdgcn_mfma_f32_16x16x32_bf16(af[i], bfr[j], acc[i][j], 0, 0, 0);
    }
  }

  if (EPI == 0) {
    bf16_t* C = (bf16_t*)(kz == 0 ? C0 : C1);   // bf16 partial destinations
    #pragma unroll
    for (int i = 0; i < 4; ++i)
      #pragma unroll
      for (int j = 0; j < 4; ++j)
        #pragma unroll
        for (int r = 0; r < 4; ++r) {
          int m = m0 + wy * 64 + i * 16 + quad * 4 + r;
          int n = n0 + wx * 64 + j * 16 + l15;
          C[(size_t)m * 1024 + n] = (bf16_t)acc[i][j][r];
        }
  } else {
    int nb = n0 + wx * 64;
    int which = nb >> 10;              // 0=q, 1=k, 2=v
    int head = (nb & 1023) >> 6;
    const int bq = m0 >> 11;           // batch (uniform per block: m0 multiple of 128)
    const int mb = (m0 & 2047) + wy * 64;
    if (which == 2) {
      // V: write transposed directly -> vT[b,h,d,pos]. acc[i][j][r] has r
      // contiguous in pos, so each lane stores a bf16x4 along pos.
      bf16_t* dst = (bf16_t*)C2 + ((size_t)(bq * 16 + head)) * 64 * 2048;
      #pragma unroll
      for (int i = 0; i < 4; ++i)
        #pragma unroll
        for (int j = 0; j < 4; ++j) {
          bf16x4 pk;
          #pragma unroll
          for (int r = 0; r < 4; ++r) pk[r] = (bf16_t)acc[i][j][r];
          int d = j * 16 + l15;
          int pos = mb + i * 16 + quad * 4;
          *(bf16x4*)(dst + (size_t)d * 2048 + pos) = pk;
        }
    } else {
      bf16_t* dst = which == 0 ? (bf16_t*)C0 : (bf16_t*)C1;
      float sc = which == 0 ? 0.125f : 1.0f;
      #pragma unroll
      for (int i = 0; i < 4; ++i)
        #pragma unroll
        for (int j = 0; j < 4; ++j)
          #pragma unroll
          for (int r = 0; r < 4; ++r) {
            int pos = mb + i * 16 + quad * 4 + r;
            int d = j * 16 + l15;
            dst[(((size_t)(bq * 16 + head)) * 2048 + pos) * 64 + d] =
                (bf16_t)(acc[i][j][r] * sc);
          }
    }
  }
}

// ---------------------------------------------------------------------------
// Causal ReLU attention, R13: R11 structure + per-unit Ss double-buffer.
// Block (h=bx, j=by in [0,8), b=bz) handles rows {2j, 2j+1, 30-2j, 31-2j}:
//   waves 0-3 = pair-lo (rows 2j, 2j+1), waves 4-7 = pair-hi (30-2j, 31-2j).
// Per block: 66 MFMA tile-units, uniform in j. Tiles 0..31-2j staged once
// each (2/iteration, dbuf). Per tile: sU(s0); sU(s1); wU(s0->SsA);
// wU(s1->SsB); pU(acc0<-SsA); pU(acc1<-SsB) — unit1's Ss write->read
// latency hides under unit0's PV MFMAs. 256 blocks = 1/CU. LDS 100 KB.
// ---------------------------------------------------------------------------
__global__ __launch_bounds__(512, 2) void attn_kernel(
    const bf16_t* __restrict__ q, const bf16_t* __restrict__ k,
    const bf16_t* __restrict__ vT, bf16_t* __restrict__ out) {
  __shared__ __align__(16) bf16_t Ks[2][2][64 * 64];   // [dbuf][tile] 32 KB
  __shared__ __align__(16) bf16_t Vts[2][2][64 * 64];  // 32 KB
  __shared__ __align__(16) bf16_t Ss[2][2][64 * 72];   // [pair][unit] 36 KB

  const int h = blockIdx.x, j = blockIdx.y, b = blockIdx.z;
  const int t = threadIdx.x;
  const int w = t >> 6, l = t & 63, l15 = l & 15, quad = l >> 4;
  const int pairSel = w >> 2;          // 0 = lo, 1 = hi
  const int wl = w & 3;                // wave within pair-group (16 queries)
  const size_t bh = (size_t)(b * 16 + h);
  const int r0 = pairSel ? 30 - 2 * j : 2 * j;
  const int r1 = r0 + 1;
  const int niter = 16 - j;            // tiles 0..31-2j, two per iteration

  const int r_l = l >> 3;              // row within 8-row chunk
  const int u_g = (l & 7) ^ r_l;       // swizzled source 8-elem unit
  const int rswz = l15 & 7;            // read-side swizzle key

  // stage 2 tiles (2*i2, 2*i2+1): 32 async ops spread over 8 waves
  auto stage_pair = [&](int buf, int i2) {
    #pragma unroll
    for (int c = 0; c < 4; ++c) {
      int op = w * 4 + c;              // 0..31
      int tau = op >> 4;               // which of the 2 tiles
      int rem = op & 15;
      int mK = rem >> 3;               // 0 = K, 1 = V
      int idx = rem & 7;               // chunk within tile
      int kt = 2 * i2 + tau;
      int row = idx * 8 + r_l;         // 0..63
      if (mK == 0)
        async_copy16(&Ks[buf][tau][idx * 512],
                     k + (bh * 2048 + kt * 64 + row) * 64 + u_g * 8);
      else
        async_copy16(&Vts[buf][tau][idx * 512],
                     vT + (bh * 64 + row) * 2048 + kt * 64 + u_g * 8);
    }
  };

  // read a staged tile's K/V fragments from LDS (once per tile, per wave)
  auto load_lds = [&](const bf16_t* Kb, const bf16_t* Vb,
                      bf16x8 (&bk)[2][4], bf16x8 (&bv)[2][4]) {
    #pragma unroll
    for (int kk = 0; kk < 2; ++kk)
      #pragma unroll
      for (int tj = 0; tj < 4; ++tj) {
        int u = ((kk * 4 + quad) ^ rswz) * 8;
        bk[kk][tj] = *(const bf16x8*)&Kb[(tj * 16 + l15) * 64 + u];
        bv[kk][tj] = *(const bf16x8*)&Vb[(tj * 16 + l15) * 64 + u];
      }
  };

  bf16x8 qa[2][2];   // B-operand fragments: lane l15 = query row, k = d
  {
    #pragma unroll
    for (int kk = 0; kk < 2; ++kk) {
      qa[0][kk] = *(const bf16x8*)(q + (bh * 2048 + r0 * 64 + wl * 16 + l15) * 64 + kk * 32 + quad * 8);
      qa[1][kk] = *(const bf16x8*)(q + (bh * 2048 + r1 * 64 + wl * 16 + l15) * 64 + kk * 32 + quad * 8);
    }
  }

  // acc[tj] = O^T block: lane col = pos (l15), regs = d = tj*16 + quad*4 + r
  f32x4 acc0[4], acc1[4];
  #pragma unroll
  for (int tj = 0; tj < 4; ++tj) { acc0[tj] = (f32x4)0.0f; acc1[tj] = (f32x4)0.0f; }

  // S^T matmul into registers (no LDS)
  auto sU = [&](f32x4 (&sacc)[4], bf16x8 (&qf)[2], bf16x8 (&bk)[2][4]) {
    #pragma unroll
    for (int tj = 0; tj < 4; ++tj) sacc[tj] = (f32x4)0.0f;
    #pragma unroll
    for (int kk = 0; kk < 2; ++kk)
      #pragma unroll
      for (int tj = 0; tj < 4; ++tj)
        sacc[tj] = __builtin_amdgcn_mfma_f32_16x16x32_bf16(bk[kk][tj], qf[kk], sacc[tj], 0, 0, 0);
  };
  // relu + mask + packed Ss write (wave-private rows of the given buffer)
  auto wU = [&](f32x4 (&sacc)[4], bool dg, bf16_t* SsBuf) {
    #pragma unroll
    for (int tj = 0; tj < 4; ++tj) {
      bf16x4 pk;
      #pragma unroll
      for (int r = 0; r < 4; ++r) {
        float v = fmaxf(sacc[tj][r], 0.0f);
        if (dg && (tj * 16 + quad * 4 + r > wl * 16 + l15)) v = 0.0f;
        pk[r] = (bf16_t)v;
      }
      *(bf16x4*)&SsBuf[(wl * 16 + l15) * 72 + tj * 16 + quad * 4] = pk;
    }
  };
  // PV: read Ss as B-fragment, O^T += V^T.S
  auto pU = [&](f32x4 (&accr)[4], bf16x8 (&bv)[2][4], const bf16_t* SsBuf) {
    #pragma unroll
    for (int kk = 0; kk < 2; ++kk) {
      bf16x8 as_ = *(const bf16x8*)&SsBuf[(wl * 16 + l15) * 72 + kk * 32 + quad * 8];
      #pragma unroll
      for (int tj = 0; tj < 4; ++tj)
        accr[tj] = __builtin_amdgcn_mfma_f32_16x16x32_bf16(bv[kk][tj], as_, accr[tj], 0, 0, 0);
    }
  };

  bf16_t* SsA = &Ss[pairSel][0][0];
  bf16_t* SsB = &Ss[pairSel][1][0];

  stage_pair(0, 0);
  for (int i = 0; i < niter; ++i) {
    __syncthreads();  // drains this buffer's async loads; fences reuse
    if (i + 1 < niter) stage_pair((i + 1) & 1, i + 1);
    const int buf = i & 1;
    #pragma unroll
    for (int tau = 0; tau < 2; ++tau) {
      const int kt = 2 * i + tau;
      if (kt > r1) continue;           // wave-uniform guard
      bf16x8 bk[2][4], bv[2][4];
      load_lds(Ks[buf][tau], Vts[buf][tau], bk, bv);
      if (kt < r1) {
        // tile feeds both units (unit0 diagonal-masked on kt == r0)
        f32x4 s0[4], s1[4];
        sU(s0, qa[0], bk);             // independent MFMA streams back-to-back
        sU(s1, qa[1], bk);
        wU(s0, kt == r0, SsA);         // both Ss writes first...
        wU(s1, false, SsB);
        pU(acc0, bv, SsA);             // ...then both PV streams: SsB's
        pU(acc1, bv, SsB);             // round-trip hides under pU(acc0)
      } else {
        // kt == r1: unit1's diagonal tile only
        f32x4 s1[4];
        sU(s1, qa[1], bk);
        wU(s1, true, SsB); pU(acc1, bv, SsB);
      }
    }
  }

  // epilogue: O^T regs -> out[b][pos][h*64+d], 4 d-contiguous per store
  #pragma unroll
  for (int tj = 0; tj < 4; ++tj) {
    bf16x4 p0, p1;
    #pragma unroll
    for (int r = 0; r < 4; ++r) { p0[r] = (bf16_t)acc0[tj][r]; p1[r] = (bf16_t)acc1[tj][r]; }
    int posA = r0 * 64 + wl * 16 + l15;
    int posB = r1 * 64 + wl * 16 + l15;
    int col = h * 64 + tj * 16 + quad * 4;
    *(bf16x4*)(out + ((size_t)b * 2048 + posA) * 1024 + col) = p0;
    *(bf16x4*)(out + ((size_t)b * 2048 + posB) * 1024 + col) = p1;
  }
}

// ---------------------------------------------------------------------------
// launch
// ---------------------------------------------------------------------------
extern "C" void kernel_launch(void* const* d_in, const int* in_sizes, int n_in,
                              void* d_out, int out_size, void* d_ws, size_t ws_size,
                              hipStream_t stream) {
  (void)in_sizes; (void)n_in; (void)out_size; (void)ws_size;
  const float* x     = (const float*)d_in[0];
  const float* ln1_g = (const float*)d_in[1];
  const float* ln1_b = (const float*)d_in[2];
  const float* w_qkv = (const float*)d_in[3];
  const float* w_out = (const float*)d_in[4];
  const float* ln2_g = (const float*)d_in[5];
  const float* ln2_b = (const float*)d_in[6];
  float* out = (float*)d_out;

  char* ws = (char*)d_ws;
  bf16_t* xn     = (bf16_t*)(ws + 0);          //  8,388,608  [4096,1024]
  bf16_t* wqkvT  = (bf16_t*)(ws + 8388608);    //  6,291,456  [3072,1024]
  bf16_t* woutT  = (bf16_t*)(ws + 14680064);   //  2,097,152  [1024,1024]
  bf16_t* qb     = (bf16_t*)(ws + 16777216);   //  8,388,608  [2,16,2048,64]
  bf16_t* kb     = (bf16_t*)(ws + 25165824);   //  8,388,608
  bf16_t* vTb    = (bf16_t*)(ws + 41943040);   //  8,388,608  [2,16,64,2048] (written by QKV epilogue)
  bf16_t* ao     = (bf16_t*)(ws + 50331648);   //  8,388,608  [4096,1024]
  bf16_t* zb0    = (bf16_t*)(ws + 58720256);   //  8,388,608  [4096,1024] bf16 partial
  bf16_t* zb1    = (bf16_t*)(ws + 67108864);   //  8,388,608  bf16 partial

  prep_kernel<<<5120, 256, 0, stream>>>(x, ln1_g, ln1_b, xn, w_qkv, wqkvT, w_out, woutT);
  gemm128_kernel<1, 1><<<dim3(24, 32), 256, 0, stream>>>(xn, wqkvT, qb, kb, vTb);
  attn_kernel<<<dim3(16, 8, 2), 512, 0, stream>>>(qb, kb, vTb, ao);
  gemm128_kernel<0, 2><<<dim3(8, 32, 2), 256, 0, stream>>>(ao, woutT, zb0, zb1, nullptr);
  ln2_kernel<<<4096, 256, 0, stream>>>(zb0, zb1, ln2_g, ln2_b, out);
}